// Round 2
// baseline (287.475 us; speedup 1.0000x reference)
//
#include <hip/hip_runtime.h>

// MoE combiner: out[i,:] = sum_e gates[i,e] * expert_outputs[e,:]
// expert_outputs: [64, 4096] f32   (d_in[0])
// gates:          [16384, 64] f32  (d_in[1], exactly top-2 nonzero per row)
// out:            [16384, 4096] f32
//
// v2 theory: the 268 MB NT-store stream thrashes the 4 MB per-XCD L2, so
// the ~512 MB of logical expert-row re-reads miss to HBM (268+512 ~= 780 MB
// @ ~7.2 TB/s ~= the observed ~108 us). Fix: stage experts in LDS so the
// read path never touches L2/HBM after a one-time 64 KB per-block stage.
//
// Structure: block = 256-float column chunk x 256 rows.
//   phase 1: stage expert[:, chunk] (64 experts x 256 f32 = 64 KB) into LDS;
//            in parallel, precompute per-row routing (e0,e1,g0,g1) via
//            batched ballots into LDS. One barrier.
//   phase 2: per row: 2 LDS v4f reads + fma + 1 KB coalesced NT store.
//            Zero global reads. Store stream is the only HBM traffic.
// HBM total ~= 268 MB writes + ~16 MB expert stage + ~64 MB gates.

#define NUM_EXPERTS 64
#define D_MODEL 4096
#define NUM_IMAGES 16384
#define D4 (D_MODEL / 4)            // 1024 v4f per row
#define CHUNK 256                   // floats per column chunk
#define CHUNK4 (CHUNK / 4)          // 64 v4f per chunk
#define NCHUNK (D_MODEL / CHUNK)    // 16 chunks
#define RPB 256                     // rows per block

typedef float v4f __attribute__((ext_vector_type(4)));

__global__ __launch_bounds__(256) void moe_combine_kernel(
    const float* __restrict__ expert,   // [64, 4096]
    const float* __restrict__ gates,    // [16384, 64]
    float* __restrict__ out)            // [16384, 4096]
{
    const int tid  = threadIdx.x;
    const int w    = tid >> 6;          // wave 0..3
    const int lane = tid & 63;

    const int chunk  = blockIdx.x & (NCHUNK - 1);   // consecutive blocks spread chunks
    const int rgroup = blockIdx.x >> 4;             // blockIdx / NCHUNK
    const int row0   = rgroup * RPB;

    __shared__ v4f   Elds[NUM_EXPERTS][CHUNK4];     // 64 KB: expert[:, chunk]
    __shared__ float sg0[RPB], sg1[RPB];            // 2 KB
    __shared__ int   se0[RPB], se1[RPB];            // 2 KB  (se0 = -1 => fallback)

    // ---- phase 1a: stage expert column chunk into LDS (coalesced v4f) ----
    {
        const v4f* __restrict__ Ev = (const v4f*)expert;
        const size_t cbase = (size_t)chunk * CHUNK4;
        #pragma unroll
        for (int k = 0; k < (NUM_EXPERTS * CHUNK4) / 256; ++k) {   // 16 iters
            const int idx = (k << 8) | tid;         // flat v4f index in chunk
            const int e = idx >> 6;                 // expert row
            const int j = idx & 63;                 // v4f col within chunk
            Elds[e][j] = Ev[(size_t)e * D4 + cbase + j];
        }
    }

    // ---- phase 1b: routing for this block's 256 rows (wave w owns 64) ----
    {
        const int lrbase = w << 6;                  // w*64
        for (int b = 0; b < 64; b += 8) {
            float gv[8];
            #pragma unroll
            for (int i = 0; i < 8; ++i)             // 8 independent loads in flight
                gv[i] = gates[(size_t)(row0 + lrbase + b + i) * NUM_EXPERTS + lane];
            #pragma unroll
            for (int i = 0; i < 8; ++i) {
                const int lr = lrbase + b + i;
                const unsigned long long m = __ballot(gv[i] != 0.0f);
                if (__popcll(m) == 2) {
                    const int ea = __ffsll(m) - 1;          // lowest set bit
                    const int eb = 63 - __clzll(m);         // highest set bit
                    const float ga = __shfl(gv[i], ea);
                    const float gb = __shfl(gv[i], eb);
                    if (lane == 0) {
                        se0[lr] = ea; se1[lr] = eb;
                        sg0[lr] = ga; sg1[lr] = gb;
                    }
                } else if (lane == 0) {
                    se0[lr] = -1;                           // generic fallback
                }
            }
        }
    }

    __syncthreads();

    // ---- phase 2: stream the output. Reads only from LDS. ----
    {
        v4f* __restrict__ O = (v4f*)out;
        const int lrbase = w << 6;
        const size_t obase = (size_t)row0 * D4 + (size_t)chunk * CHUNK4 + lane;
        #pragma unroll 4
        for (int i = 0; i < 64; ++i) {
            const int lr = lrbase + i;
            const int e0 = se0[lr];                 // wave-uniform broadcast read
            v4f acc;
            if (e0 >= 0) {
                acc = sg0[lr] * Elds[e0][lane] + sg1[lr] * Elds[se1[lr]][lane];
            } else {
                // never taken for top-2 routing; correct for any gate row
                acc = (v4f)(0.0f);
                for (int e = 0; e < NUM_EXPERTS; ++e)
                    acc += gates[(size_t)(row0 + lr) * NUM_EXPERTS + e] * Elds[e][lane];
            }
            __builtin_nontemporal_store(acc, &O[obase + (size_t)lr * D4]);
        }
    }
}

extern "C" void kernel_launch(void* const* d_in, const int* in_sizes, int n_in,
                              void* d_out, int out_size, void* d_ws, size_t ws_size,
                              hipStream_t stream) {
    const float* expert = (const float*)d_in[0];  // [64, 4096]
    const float* gates  = (const float*)d_in[1];  // [16384, 64]
    float* out = (float*)d_out;                   // [16384, 4096]

    dim3 grid(NCHUNK * (NUM_IMAGES / RPB));       // 16 * 64 = 1024 blocks
    dim3 block(256);
    moe_combine_kernel<<<grid, block, 0, stream>>>(expert, gates, out);
}

// Round 3
// 280.639 us; speedup vs baseline: 1.0244x; 1.0244x over previous
//
#include <hip/hip_runtime.h>

// MoE combiner: out[i,:] = sum_e gates[i,e] * expert_outputs[e,:]
// expert_outputs: [64, 4096] f32   (d_in[0])
// gates:          [16384, 64] f32  (d_in[1], exactly top-2 nonzero per row)
// out:            [16384, 4096] f32
//
// v3 = v2 with ONE change: plain stores instead of __builtin_nontemporal_store.
// A/B probe: three structurally different kernels (R0/R1/R2) all pinned at
// ~108-119 us with NT stores => implied store BW ~2.5 TB/s, vs 6.4 TB/s for
// the harness's plain-store fill. Theory T2: the nt store path throttles.
// The hot loop reads ONLY LDS here, so plain-store L2 allocation cannot
// thrash anything the read path needs -- this isolates the store path.
//
// Structure (unchanged from v2): block = 256-float column chunk x 256 rows.
//   phase 1: stage expert[:, chunk] (64 KB) into LDS + per-row routing via
//            batched ballots. One barrier.
//   phase 2: per row: 2 LDS v4f reads + fma + 1 KB coalesced store.

#define NUM_EXPERTS 64
#define D_MODEL 4096
#define NUM_IMAGES 16384
#define D4 (D_MODEL / 4)            // 1024 v4f per row
#define CHUNK 256                   // floats per column chunk
#define CHUNK4 (CHUNK / 4)          // 64 v4f per chunk
#define NCHUNK (D_MODEL / CHUNK)    // 16 chunks
#define RPB 256                     // rows per block

typedef float v4f __attribute__((ext_vector_type(4)));

__global__ __launch_bounds__(256) void moe_combine_kernel(
    const float* __restrict__ expert,   // [64, 4096]
    const float* __restrict__ gates,    // [16384, 64]
    float* __restrict__ out)            // [16384, 4096]
{
    const int tid  = threadIdx.x;
    const int w    = tid >> 6;          // wave 0..3
    const int lane = tid & 63;

    const int chunk  = blockIdx.x & (NCHUNK - 1);
    const int rgroup = blockIdx.x >> 4;             // blockIdx / NCHUNK
    const int row0   = rgroup * RPB;

    __shared__ v4f   Elds[NUM_EXPERTS][CHUNK4];     // 64 KB: expert[:, chunk]
    __shared__ float sg0[RPB], sg1[RPB];            // 2 KB
    __shared__ int   se0[RPB], se1[RPB];            // 2 KB  (se0 = -1 => fallback)

    // ---- phase 1a: stage expert column chunk into LDS (coalesced v4f) ----
    {
        const v4f* __restrict__ Ev = (const v4f*)expert;
        const size_t cbase = (size_t)chunk * CHUNK4;
        #pragma unroll
        for (int k = 0; k < (NUM_EXPERTS * CHUNK4) / 256; ++k) {   // 16 iters
            const int idx = (k << 8) | tid;         // flat v4f index in chunk
            const int e = idx >> 6;                 // expert row
            const int j = idx & 63;                 // v4f col within chunk
            Elds[e][j] = Ev[(size_t)e * D4 + cbase + j];
        }
    }

    // ---- phase 1b: routing for this block's 256 rows (wave w owns 64) ----
    {
        const int lrbase = w << 6;                  // w*64
        for (int b = 0; b < 64; b += 8) {
            float gv[8];
            #pragma unroll
            for (int i = 0; i < 8; ++i)             // 8 independent loads in flight
                gv[i] = gates[(size_t)(row0 + lrbase + b + i) * NUM_EXPERTS + lane];
            #pragma unroll
            for (int i = 0; i < 8; ++i) {
                const int lr = lrbase + b + i;
                const unsigned long long m = __ballot(gv[i] != 0.0f);
                if (__popcll(m) == 2) {
                    const int ea = __ffsll(m) - 1;          // lowest set bit
                    const int eb = 63 - __clzll(m);         // highest set bit
                    const float ga = __shfl(gv[i], ea);
                    const float gb = __shfl(gv[i], eb);
                    if (lane == 0) {
                        se0[lr] = ea; se1[lr] = eb;
                        sg0[lr] = ga; sg1[lr] = gb;
                    }
                } else if (lane == 0) {
                    se0[lr] = -1;                           // generic fallback
                }
            }
        }
    }

    __syncthreads();

    // ---- phase 2: stream the output. Reads only from LDS. PLAIN stores. ----
    {
        v4f* __restrict__ O = (v4f*)out;
        const int lrbase = w << 6;
        const size_t obase = (size_t)row0 * D4 + (size_t)chunk * CHUNK4 + lane;
        #pragma unroll 4
        for (int i = 0; i < 64; ++i) {
            const int lr = lrbase + i;
            const int e0 = se0[lr];                 // wave-uniform broadcast read
            v4f acc;
            if (e0 >= 0) {
                acc = sg0[lr] * Elds[e0][lane] + sg1[lr] * Elds[se1[lr]][lane];
            } else {
                // never taken for top-2 routing; correct for any gate row
                acc = (v4f)(0.0f);
                for (int e = 0; e < NUM_EXPERTS; ++e)
                    acc += gates[(size_t)(row0 + lr) * NUM_EXPERTS + e] * Elds[e][lane];
            }
            O[obase + (size_t)lr * D4] = acc;       // plain store (the A/B variable)
        }
    }
}

extern "C" void kernel_launch(void* const* d_in, const int* in_sizes, int n_in,
                              void* d_out, int out_size, void* d_ws, size_t ws_size,
                              hipStream_t stream) {
    const float* expert = (const float*)d_in[0];  // [64, 4096]
    const float* gates  = (const float*)d_in[1];  // [16384, 64]
    float* out = (float*)d_out;                   // [16384, 4096]

    dim3 grid(NCHUNK * (NUM_IMAGES / RPB));       // 16 * 64 = 1024 blocks
    dim3 block(256);
    moe_combine_kernel<<<grid, block, 0, stream>>>(expert, gates, out);
}

// Round 4
// 276.548 us; speedup vs baseline: 1.0395x; 1.0148x over previous
//
#include <hip/hip_runtime.h>

// MoE combiner: out[i,:] = sum_e gates[i,e] * expert_outputs[e,:]
// expert_outputs: [64, 4096] f32   (d_in[0])
// gates:          [16384, 64] f32  (d_in[1], exactly top-2 nonzero per row)
// out:            [16384, 4096] f32
//
// v4 = v1 (wave-per-row, best structure at 276.2) with ONE change:
// plain stores instead of __builtin_nontemporal_store.
// Rationale: R2(NT)=287.5 vs R3(plain)=280.6 showed plain stores are ~7 us
// faster when the read path doesn't depend on L2. The expert re-reads that
// miss L2 are absorbed by the 256 MB L3 (FETCH_SIZE counts HBM only), so
// L2 write-protection via NT was likely never load-bearing. One-variable A/B
// on the best structure.
//
// Structure: ONE WAVE = ONE ROW. No LDS, no barriers. Ballot-derived top-2
// routing, shfl broadcast, 16 coalesced 1 KB store iterations per row.

#define NUM_EXPERTS 64
#define D_MODEL 4096
#define NUM_IMAGES 16384
#define D4 (D_MODEL / 4)          // 1024 float4 per row
#define ROWS_PER_BLOCK 4          // 4 waves per 256-thread block

typedef float v4f __attribute__((ext_vector_type(4)));

__global__ __launch_bounds__(256) void moe_combine_kernel(
    const float* __restrict__ expert,   // [64, 4096]
    const float* __restrict__ gates,    // [16384, 64]
    float* __restrict__ out)            // [16384, 4096]
{
    const int wave = threadIdx.x >> 6;
    const int lane = threadIdx.x & 63;
    const int row  = blockIdx.x * ROWS_PER_BLOCK + wave;

    const float g = gates[(size_t)row * NUM_EXPERTS + lane];
    const unsigned long long m = __ballot(g != 0.0f);
    const int cnt = __popcll(m);

    const v4f* __restrict__ E = (const v4f*)expert;
    v4f* __restrict__ Orow = (v4f*)out + (size_t)row * D4;

    if (cnt == 2) {
        // Fast path: exactly top-2 nonzero (always, for this routing).
        // m is wave-uniform, so this branch is non-divergent and __shfl is safe.
        const int e0 = __ffsll(m) - 1;          // lowest set bit
        const int e1 = 63 - __clzll(m);         // highest set bit
        const float g0 = __shfl(g, e0);
        const float g1 = __shfl(g, e1);
        const v4f* __restrict__ E0 = E + (size_t)e0 * D4;
        const v4f* __restrict__ E1 = E + (size_t)e1 * D4;
        #pragma unroll 4
        for (int k = 0; k < D4 / 64; ++k) {
            const int c = lane + (k << 6);      // coalesced: 64 lanes x 16 B = 1 KB/instr
            Orow[c] = g0 * E0[c] + g1 * E1[c];  // plain store (the A/B variable)
        }
    } else {
        // Generic fallback (cnt != 2), still correct. Wave-uniform trip count.
        for (int c = lane; c < D4; c += 64) {
            v4f acc = (v4f)(0.0f);
            unsigned long long mm = m;
            while (mm) {
                const int e = __ffsll(mm) - 1;
                mm &= mm - 1ull;
                const float ge = __shfl(g, e);
                acc += ge * E[(size_t)e * D4 + c];
            }
            Orow[c] = acc;
        }
    }
}

extern "C" void kernel_launch(void* const* d_in, const int* in_sizes, int n_in,
                              void* d_out, int out_size, void* d_ws, size_t ws_size,
                              hipStream_t stream) {
    const float* expert = (const float*)d_in[0];  // [64, 4096]
    const float* gates  = (const float*)d_in[1];  // [16384, 64]
    float* out = (float*)d_out;                   // [16384, 4096]

    dim3 grid(NUM_IMAGES / ROWS_PER_BLOCK);       // 4096 blocks, 1 wave per row
    dim3 block(256);
    moe_combine_kernel<<<grid, block, 0, stream>>>(expert, gates, out);
}